// Round 17
// baseline (197.577 us; speedup 1.0000x reference)
//
#include <hip/hip_runtime.h>

typedef __attribute__((ext_vector_type(4))) float f32x4;
typedef __attribute__((ext_vector_type(8))) short s16x8;

__device__ __forceinline__ ushort f2bf(float f) {
  unsigned u = __float_as_uint(f);
  return (ushort)((u + 0x7fffu + ((u >> 16) & 1u)) >> 16);
}

// ---------------- merged f32 -> bf16 conversion (enc, fq, 4 weights) ----------
__global__ __launch_bounds__(256) void cvt_all(
    const float4* __restrict__ enc, const float4* __restrict__ fq,
    const float4* __restrict__ wq, const float4* __restrict__ wk,
    const float4* __restrict__ wv, const float4* __restrict__ wo,
    ushort* __restrict__ enc16, ushort* __restrict__ fq16,
    ushort* __restrict__ wq16, ushort* __restrict__ wk16,
    ushort* __restrict__ wv16, ushort* __restrict__ wo16) {
  const int stride = gridDim.x * 256;
  for (int i = blockIdx.x * 256 + threadIdx.x; i < 6291456; i += stride) {
    const float4* src;
    ushort* dst;
    int k;
    if (i < 4194304) {
      src = enc; dst = enc16; k = i;
    } else if (i < 5242880) {
      src = fq; dst = fq16; k = i - 4194304;
    } else {
      const int j = i - 5242880, sel = j >> 18;
      k = j & 262143;
      src = sel == 0 ? wq : sel == 1 ? wk : sel == 2 ? wv : wo;
      dst = sel == 0 ? wq16 : sel == 1 ? wk16 : sel == 2 ? wv16 : wo16;
    }
    float4 v = src[k];
    uint2 o;
    o.x = (unsigned)f2bf(v.x) | ((unsigned)f2bf(v.y) << 16);
    o.y = (unsigned)f2bf(v.z) | ((unsigned)f2bf(v.w) << 16);
    *(uint2*)(dst + (size_t)k * 4) = o;
  }
}

__device__ __forceinline__ void gload_lds16(const void* g, void* l) {
  __builtin_amdgcn_global_load_lds((const __attribute__((address_space(1))) void*)g,
                                   (__attribute__((address_space(3))) void*)l, 16, 0, 0);
}

// ====== fused K+V+Q projections: 256x256 tile, 8-wave, 8-phase (R8 config) ===
// R17: panel order reversed so V blocks (never skip) occupy bids 0-255 —
// guaranteed work is front-loaded, skip-heavy K blocks drain at the tail.
__global__ __launch_bounds__(512, 1) void gemm256_fused(
    const ushort* __restrict__ enc16, const ushort* __restrict__ fq16,
    const ushort* __restrict__ Bkv, const ushort* __restrict__ Bq,
    const float* __restrict__ wk_b, const float* __restrict__ wv_b,
    const float* __restrict__ wq_b,
    ushort* __restrict__ Ko, ushort* __restrict__ Vt, ushort* __restrict__ Qo,
    float* __restrict__ Tsum, const int* __restrict__ dlen,
    const int* __restrict__ elen, float qscale) {
  __shared__ char lds[131072];  // A: 2dbuf x 2half x 16KB @0 ; B same @64KB
  const int tid = threadIdx.x;
  const int lane = tid & 63, wid = tid >> 6;
  const int g = lane >> 4, r = lane & 15;
  const int wm = wid >> 2, wn = wid & 3;
  const int bid = blockIdx.x;

  const ushort* Amat;
  const ushort* Bmat;
  int m0, n0, role;  // 0=K, 1=V, 2=Q
  if (bid < 512) {
    const int xcd = bid & 7, inner = bid >> 3;
    m0 = (xcd * 8 + (inner & 7)) * 256;   // XCD owns 8 consecutive m-tiles (A reuse)
    n0 = (7 - (inner >> 3)) * 256;        // panels reversed: V (4-7) first, K (0-3) last
    Amat = enc16;
    Bmat = Bkv;
    if (n0 < 1024) {
      role = 0;
      if ((m0 & 2047) >= elen[m0 >> 11]) return;  // dead K rows
    } else {
      role = 1;  // V always computed (Tsum needs all tiles)
    }
  } else {
    const int q = bid - 512;
    m0 = (q & 15) * 256;
    n0 = (q >> 4) * 256;
    Amat = fq16;
    Bmat = Bq;
    role = 2;
    if ((m0 & 511) >= dlen[m0 >> 9]) return;  // dead Q rows
  }
  const size_t rowb = 2048;  // K=1024 bf16

  // staging source: row = srow (+64 per second load, +128 per half), col pre-XORed
  const int srow = tid >> 3;
  const int scb = (((tid & 7) ^ (srow & 7)) << 4);
  const char* Asrc = (const char*)Amat + (size_t)(m0 + srow) * rowb + scb;
  const char* Bsrc = (const char*)Bmat + (size_t)(n0 + srow) * rowb + scb;

  auto sAh = [&](int kt, int h) {
    char* d0 = lds + (kt & 1) * 32768 + h * 16384 + tid * 16;
    const char* s0 = Asrc + (size_t)(h * 128) * rowb + (size_t)kt * 128;
    gload_lds16(s0, d0);
    gload_lds16(s0 + (size_t)64 * rowb, d0 + 8192);
  };
  auto sBh = [&](int kt, int h) {
    char* d0 = lds + 65536 + (kt & 1) * 32768 + h * 16384 + tid * 16;
    const char* s0 = Bsrc + (size_t)(h * 128) * rowb + (size_t)kt * 128;
    gload_lds16(s0, d0);
    gload_lds16(s0 + (size_t)64 * rowb, d0 + 8192);
  };

  const int cb0 = (g * 16) ^ ((r & 7) << 4);
  const int cb1 = (64 + g * 16) ^ ((r & 7) << 4);

  f32x4 acc[8][4] = {};

  // prologue: kt0 A+B, kt1 B (kt1 A staged in iter0 p1,p2)
  sAh(0, 0); sAh(0, 1); sBh(0, 0); sBh(0, 1); sBh(1, 0); sBh(1, 1);
  asm volatile("s_waitcnt vmcnt(4)" ::: "memory");
  __builtin_amdgcn_s_barrier();

#define MFMA_(a, b, c) __builtin_amdgcn_mfma_f32_16x16x32_bf16(a, b, c, 0, 0, 0)
#define PH(AB, Q, STAGE, WAIT)                                                 \
  {                                                                            \
    s16x8 aq0 = *(const s16x8*)(AB + (2 * (Q)) * 2048 + cb0);                  \
    s16x8 aq1 = *(const s16x8*)(AB + (2 * (Q)) * 2048 + cb1);                  \
    s16x8 aq2 = *(const s16x8*)(AB + (2 * (Q) + 1) * 2048 + cb0);              \
    s16x8 aq3 = *(const s16x8*)(AB + (2 * (Q) + 1) * 2048 + cb1);              \
    STAGE;                                                                     \
    __builtin_amdgcn_s_barrier();                                              \
    asm volatile("s_waitcnt lgkmcnt(0)" ::: "memory");                         \
    __builtin_amdgcn_sched_barrier(0);                                         \
    __builtin_amdgcn_s_setprio(1);                                             \
    _Pragma("unroll") for (int ni = 0; ni < 4; ++ni)                           \
        acc[2 * (Q)][ni] = MFMA_(aq0, bfr[ni][0], acc[2 * (Q)][ni]);           \
    _Pragma("unroll") for (int ni = 0; ni < 4; ++ni)                           \
        acc[2 * (Q) + 1][ni] = MFMA_(aq2, bfr[ni][0], acc[2 * (Q) + 1][ni]);   \
    _Pragma("unroll") for (int ni = 0; ni < 4; ++ni)                           \
        acc[2 * (Q)][ni] = MFMA_(aq1, bfr[ni][1], acc[2 * (Q)][ni]);           \
    _Pragma("unroll") for (int ni = 0; ni < 4; ++ni)                           \
        acc[2 * (Q) + 1][ni] = MFMA_(aq3, bfr[ni][1], acc[2 * (Q) + 1][ni]);   \
    __builtin_amdgcn_s_setprio(0);                                             \
    WAIT;                                                                      \
    __builtin_amdgcn_s_barrier();                                              \
  }
#define LOADB(BB)                                                              \
  _Pragma("unroll") for (int ni = 0; ni < 4; ++ni) {                           \
    bfr[ni][0] = *(const s16x8*)(BB + ni * 2048 + cb0);                        \
    bfr[ni][1] = *(const s16x8*)(BB + ni * 2048 + cb1);                        \
  }

  const int NIT = 8;  // K=1024: 8 super-iters (2 K-tiles each)
  const char* AbB = lds + wm * 16384 + r * 128;
  const char* BbB = lds + 65536 + (wn >> 1) * 16384 + (wn & 1) * 8192 + r * 128;

  for (int it = 0; it < NIT; ++it) {
    const bool st = (it + 1 < NIT);
    const int k1 = 2 * it + 1, k2 = 2 * it + 2, k3 = 2 * it + 3;
    s16x8 bfr[4][2];
    // ---- half 0: kt = 2it from dbuf0
    LOADB(BbB);
    PH(AbB, 0, sAh(k1, 0), );
    PH(AbB, 1, sAh(k1, 1), );
    PH(AbB, 2, if (st) sBh(k2, 0), );
    PH(AbB, 3, if (st) sBh(k2, 1),
       if (st) { asm volatile("s_waitcnt vmcnt(4)" ::: "memory"); } else {
         asm volatile("s_waitcnt vmcnt(0)" ::: "memory");
       });
    // ---- half 1: kt = 2it+1 from dbuf1
    const char* Ab1 = AbB + 32768;
    const char* Bb1 = BbB + 32768;
    LOADB(Bb1);
    PH(Ab1, 0, if (st) sAh(k2, 0), );
    PH(Ab1, 1, if (st) sAh(k2, 1), );
    PH(Ab1, 2, if (st) sBh(k3, 0), );
    PH(Ab1, 3, if (st) sBh(k3, 1),
       if (st) { asm volatile("s_waitcnt vmcnt(4)" ::: "memory"); });
  }
#undef PH
#undef LOADB
#undef MFMA_

  // ---- epilogue: acc row = m0 + wm*128 + i*16 + g*4 + j, col = n0 + wn*64 + ni*16 + r
  if (role != 1) {
    ushort* C = (role == 2) ? Qo : Ko;
    const float* bias0 = (role == 2) ? wq_b : wk_b;
    const float sc = (role == 2) ? qscale : 1.0f;
    // bounce to LDS [row 256][col 256] bf16, 16B-slot XOR ((row>>2)&7)<<4
#pragma unroll
    for (int ni = 0; ni < 4; ++ni) {
      const int col = wn * 64 + ni * 16 + r;
      const float bv = bias0[n0 + col];
#pragma unroll
      for (int i = 0; i < 8; ++i)
#pragma unroll
        for (int j = 0; j < 4; ++j) {
          const int row = wm * 128 + i * 16 + g * 4 + j;
          *(ushort*)(lds + ((row * 512 + col * 2) ^ (((row >> 2) & 7) << 4))) =
              f2bf((acc[i][ni][j] + bv) * sc);
        }
    }
    __syncthreads();
    const int c = tid & 31, r0 = tid >> 5;
#pragma unroll
    for (int u = 0; u < 16; ++u) {
      const int row = u * 16 + r0;
      s16x8 v = *(const s16x8*)(lds + ((row * 512 + c * 16) ^ (((row >> 2) & 7) << 4)));
      *(s16x8*)(C + (size_t)(m0 + row) * 1024 + n0 + c * 8) = v;
    }
  } else {
    const int nv0 = n0 - 1024;
    const int bb = m0 >> 11, tt0 = m0 & 2047;
    // per-64-tt-tile column sums (wave-unique (q, nv): q = wm*2 + qq)
#pragma unroll
    for (int ni = 0; ni < 4; ++ni) {
      const int nv = nv0 + wn * 64 + ni * 16 + r;
      const float bv = wv_b[nv];
#pragma unroll
      for (int qq = 0; qq < 2; ++qq) {
        float s = 0.0f;
#pragma unroll
        for (int ii = 0; ii < 4; ++ii)
#pragma unroll
          for (int j = 0; j < 4; ++j) s += acc[qq * 4 + ii][ni][j];
        s += __shfl_xor(s, 16);
        s += __shfl_xor(s, 32);
        if (g == 0) {
          const int gt = (m0 + (wm * 2 + qq) * 64) >> 6;
          Tsum[((size_t)((gt >> 5) * 16 + (nv >> 6)) * 33 + (gt & 31)) * 64 + (nv & 63)] =
              s + 64.0f * bv;
        }
      }
    }
    // bounce to LDS [nv-local 256][tt-local 256] bf16, XOR ((row&7)<<4)
#pragma unroll
    for (int ni = 0; ni < 4; ++ni) {
      const int rowl = wn * 64 + ni * 16 + r;
      const float bv = wv_b[nv0 + rowl];
#pragma unroll
      for (int i = 0; i < 8; ++i)
#pragma unroll
        for (int j = 0; j < 4; ++j) {
          const int coll = wm * 128 + i * 16 + g * 4 + j;
          *(ushort*)(lds + ((rowl * 512 + coll * 2) ^ ((rowl & 7) << 4))) =
              f2bf(acc[i][ni][j] + bv);
        }
    }
    __syncthreads();
    const int c = tid & 31, r0 = tid >> 5;
#pragma unroll
    for (int u = 0; u < 16; ++u) {
      const int row = u * 16 + r0;
      s16x8 v = *(const s16x8*)(lds + ((row * 512 + c * 16) ^ ((row & 7) << 4)));
      *(s16x8*)(Vt + ((size_t)bb * 1024 + nv0 + row) * 2048 + tt0 + c * 8) = v;
    }
  }
}

// ---------------- 128x128 GEMM (O projection, f32 out) ----------------
__global__ __launch_bounds__(256) void oproj(const ushort* __restrict__ A,
                                             const ushort* __restrict__ B,
                                             const float* __restrict__ bias,
                                             float* __restrict__ C, int M, int N, int K) {
  __shared__ ushort As[128 * 32];
  __shared__ ushort Bs[128 * 32];
  const int tid = threadIdx.x;
  const int lane = tid & 63, w = tid >> 6;
  const int g = lane >> 4, r = lane & 15;
  const int m0 = blockIdx.x * 128, n0 = blockIdx.y * 128;
  const int wm = (w >> 1) * 64, wn = (w & 1) * 64;

  const int srow = tid >> 2;
  const int scb = (tid & 3) * 16;
  const char* Ag = (const char*)(A + (size_t)(m0 + srow) * K) + scb;
  const char* Bg = (const char*)(B + (size_t)(n0 + srow) * K) + scb;
  char* AsB = (char*)As + (tid & 192) * 16;
  char* BsB = (char*)Bs + (tid & 192) * 16;
  const size_t rowskip = (size_t)64 * K * sizeof(ushort);

  f32x4 acc[4][4] = {};

  for (int k0 = 0; k0 < K; k0 += 32) {
    gload_lds16(Ag + (size_t)k0 * 2, AsB);
    gload_lds16(Ag + rowskip + (size_t)k0 * 2, AsB + 4096);
    gload_lds16(Bg + (size_t)k0 * 2, BsB);
    gload_lds16(Bg + rowskip + (size_t)k0 * 2, BsB + 4096);
    __syncthreads();
    s16x8 af[4], bf[4];
#pragma unroll
    for (int i = 0; i < 4; ++i) af[i] = *(const s16x8*)&As[(wm + i * 16 + r) * 32 + g * 8];
#pragma unroll
    for (int i = 0; i < 4; ++i) bf[i] = *(const s16x8*)&Bs[(wn + i * 16 + r) * 32 + g * 8];
#pragma unroll
    for (int mi = 0; mi < 4; ++mi)
#pragma unroll
      for (int ni = 0; ni < 4; ++ni)
        acc[mi][ni] =
            __builtin_amdgcn_mfma_f32_16x16x32_bf16(af[mi], bf[ni], acc[mi][ni], 0, 0, 0);
    __syncthreads();
  }

#pragma unroll
  for (int ni = 0; ni < 4; ++ni) {
    const int n = n0 + wn + ni * 16 + r;
    const float bv = bias[n];
#pragma unroll
    for (int mi = 0; mi < 4; ++mi) {
      const int mb = m0 + wm + mi * 16 + g * 4;
#pragma unroll
      for (int j = 0; j < 4; ++j)
        C[(size_t)(mb + j) * N + n] = acc[mi][ni][j] + bv;
    }
  }
}

// suffix-sum over tiles: Vsuf[b][h][t][d] = sum_{t'>=t} tilesum  (t=0..32, [32]=0)
__global__ __launch_bounds__(64) void vsuffix(float* __restrict__ T) {
  const int bh = blockIdx.x;
  const int d = threadIdx.x;
  float* p = T + (size_t)bh * 33 * 64 + d;
  float run = 0.0f;
  p[32 * 64] = 0.0f;
  for (int t = 31; t >= 0; --t) {
    run += p[t * 64];
    p[t * 64] = run;
  }
}

// ---------------- fused masked attention (R14 + T5 setprio) ------------------
__device__ __forceinline__ ushort* swz(ushort* base, int row, int colb) {
  return (ushort*)((char*)base + row * 128 + (colb ^ ((row & 7) << 4)));
}

__global__ __launch_bounds__(256) void attn_fwd(
    const ushort* __restrict__ Q, const ushort* __restrict__ Km,
    const ushort* __restrict__ Vt, const float* __restrict__ Vsuf,
    const int* __restrict__ dlen, const int* __restrict__ elen,
    ushort* __restrict__ Oatt) {
  const int tid = threadIdx.x;
  const int lane = tid & 63, w = tid >> 6;
  const int g = lane >> 4, r = lane & 15;
  const int qt = blockIdx.x, b = blockIdx.y, h = blockIdx.z;
  const int dl = dlen[b], el = elen[b];
  const float* VS = Vsuf + (size_t)(b * 16 + h) * 33 * 64;

  if (qt * 64 >= dl) {
    const int qrow = qt * 64 + w * 16 + g * 4;
#pragma unroll
    for (int dt = 0; dt < 4; ++dt) {
      const ushort hv = f2bf(VS[dt * 16 + r] * (1.0f / 2048.0f));
#pragma unroll
      for (int j = 0; j < 4; ++j)
        Oatt[(size_t)(b * 512 + qrow + j) * 1024 + h * 64 + dt * 16 + r] = hv;
    }
    return;
  }

  __shared__ ushort Ks[64 * 64];
  __shared__ ushort Vs[64 * 64];
  __shared__ ushort Ps[4 * 16 * 64];
  ushort* PsW = Ps + w * 16 * 64;
  const int qbase = qt * 64 + w * 16;

  s16x8 qf[2];
  {
    const ushort* qp = Q + (size_t)(b * 512 + qbase + r) * 1024 + h * 64 + g * 8;
    qf[0] = *(const s16x8*)qp;
    qf[1] = *(const s16x8*)(qp + 32);
  }

  f32x4 o[4] = {};
  float lrow[4] = {0.0f, 0.0f, 0.0f, 0.0f};
  bool qok[4];
#pragma unroll
  for (int j = 0; j < 4; ++j) qok[j] = (qbase + g * 4 + j) < dl;

  const int sr = tid >> 3;
  const int sc8 = (tid & 7) * 8;
  const int scb = sc8 * 2;
  const ushort* Kg = Km + (size_t)(b * 2048 + sr) * 1024 + h * 64 + sc8;
  const ushort* Vg = Vt + ((size_t)b * 1024 + h * 64 + sr) * 2048 + sc8;

  const int t_last = (el - 1) >> 6;

  s16x8 pk0, pk1, pv0, pv1;
  {
    pk0 = *(const s16x8*)(Kg);
    pk1 = *(const s16x8*)(Kg + (size_t)32 * 1024);
    pv0 = *(const s16x8*)(Vg);
    pv1 = *(const s16x8*)(Vg + (size_t)32 * 2048);
  }

  for (int t = 0; t <= t_last; ++t) {
    *(s16x8*)swz(Ks, sr, scb) = pk0;
    *(s16x8*)swz(Ks, sr + 32, scb) = pk1;
    *(s16x8*)swz(Vs, sr, scb) = pv0;
    *(s16x8*)swz(Vs, sr + 32, scb) = pv1;
    __syncthreads();

    if (t < t_last) {
      const int kv0 = (t + 1) * 64;
      pk0 = *(const s16x8*)(Kg + (size_t)kv0 * 1024);
      pk1 = *(const s16x8*)(Kg + (size_t)(kv0 + 32) * 1024);
      pv0 = *(const s16x8*)(Vg + kv0);
      pv1 = *(const s16x8*)(Vg + (size_t)32 * 2048 + kv0);
    }

    const int kv0 = t * 64;
    float p[4][4];
#pragma unroll
    for (int nt = 0; nt < 4; ++nt) {
      f32x4 s = {};
      s16x8 kf0 = *(const s16x8*)swz(Ks, nt * 16 + r, g * 16);
      s16x8 kf1 = *(const s16x8*)swz(Ks, nt * 16 + r, 64 + g * 16);
      __builtin_amdgcn_s_setprio(1);
      s = __builtin_amdgcn_mfma_f32_16x16x32_bf16(qf[0], kf0, s, 0, 0, 0);
      s = __builtin_amdgcn_mfma_f32_16x16x32_bf16(qf[1], kf1, s, 0, 0, 0);
      __builtin_amdgcn_s_setprio(0);
      const bool kok = (kv0 + nt * 16 + r) < el;
#pragma unroll
      for (int j = 0; j < 4; ++j) {
        const float pe = __builtin_amdgcn_exp2f(s[j]);
        p[nt][j] = (kok && qok[j]) ? pe : 1.0f;
      }
    }
#pragma unroll
    for (int nt = 0; nt < 4; ++nt)
#pragma unroll
      for (int j = 0; j < 4; ++j) lrow[j] += p[nt][j];

#pragma unroll
    for (int nt = 0; nt < 4; ++nt) {
#pragma unroll
      for (int jp = 0; jp < 4; jp += 2) {
        unsigned pk;
        asm("v_cvt_pk_bf16_f32 %0, %1, %2" : "=v"(pk) : "v"(p[nt][jp]), "v"(p[nt][jp + 1]));
        *swz(PsW, g * 4 + jp, (nt * 16 + r) * 2) = (ushort)pk;
        *swz(PsW, g * 4 + jp + 1, (nt * 16 + r) * 2) = (ushort)(pk >> 16);
      }
    }

#pragma unroll
    for (int kc = 0; kc < 2; ++kc) {
      s16x8 pf = *(const s16x8*)swz(PsW, r, kc * 64 + g * 16);
      __builtin_amdgcn_s_setprio(1);
#pragma unroll
      for (int dt = 0; dt < 4; ++dt) {
        s16x8 vf = *(const s16x8*)swz(Vs, dt * 16 + r, kc * 64 + g * 16);
        o[dt] = __builtin_amdgcn_mfma_f32_16x16x32_bf16(pf, vf, o[dt], 0, 0, 0);
      }
      __builtin_amdgcn_s_setprio(0);
    }
    __syncthreads();
  }

  const float tailcnt = (float)(2048 - (t_last + 1) * 64);
  const float* VT = VS + (t_last + 1) * 64;
#pragma unroll
  for (int dt = 0; dt < 4; ++dt) {
    const float tv = VT[dt * 16 + r];
#pragma unroll
    for (int j = 0; j < 4; ++j) o[dt][j] += tv;
  }

  float inv[4];
#pragma unroll
  for (int j = 0; j < 4; ++j) {
    float s = lrow[j];
    s += __shfl_xor(s, 1);
    s += __shfl_xor(s, 2);
    s += __shfl_xor(s, 4);
    s += __shfl_xor(s, 8);
    inv[j] = 1.0f / (s + tailcnt);
  }
#pragma unroll
  for (int dt = 0; dt < 4; ++dt)
#pragma unroll
    for (int j = 0; j < 4; ++j)
      Oatt[(size_t)(b * 512 + qbase + g * 4 + j) * 1024 + h * 64 + dt * 16 + r] =
          f2bf(o[dt][j] * inv[j]);
}

// ---------------- launch ----------------
extern "C" void kernel_launch(void* const* d_in, const int* in_sizes, int n_in,
                              void* d_out, int out_size, void* d_ws, size_t ws_size,
                              hipStream_t stream) {
  const float* enc  = (const float*)d_in[0];
  const float* fq   = (const float*)d_in[1];
  const int* dlen   = (const int*)d_in[2];
  const int* elen   = (const int*)d_in[3];
  const float* wq_w = (const float*)d_in[4];
  const float* wq_b = (const float*)d_in[5];
  const float* wk_w = (const float*)d_in[6];
  const float* wk_b = (const float*)d_in[7];
  const float* wv_w = (const float*)d_in[8];
  const float* wv_b = (const float*)d_in[9];
  const float* wo_w = (const float*)d_in[10];
  const float* wo_b = (const float*)d_in[11];

  char* ws = (char*)d_ws;  // all within 128MB; attw aliases fq16 (dead by attn time)
  ushort* enc16 = (ushort*)(ws + 0);           // 32 MB
  ushort* fq16  = (ushort*)(ws + 33554432);    // 8 MB
  ushort* attw  = (ushort*)(ws + 33554432);    // alias of fq16
  ushort* wq16  = (ushort*)(ws + 41943040);    // 2 MB
  ushort* wk16  = (ushort*)(ws + 44040192);    // 2 MB  | adjacent: [wk;wv] = B concat
  ushort* wv16  = (ushort*)(ws + 46137344);    // 2 MB  |
  ushort* wo16  = (ushort*)(ws + 48234496);    // 2 MB
  float*  Vsuf  = (float*)(ws + 50331648);     // ~1.06 MB (Tsum/Vsuf)
  ushort* Qw    = (ushort*)(ws + 52428800);    // 8 MB
  ushort* Kw    = (ushort*)(ws + 60817408);    // 32 MB
  ushort* Vtw   = (ushort*)(ws + 94371840);    // 32 MB, ends 126877696 < 128MB

  cvt_all<<<4096, 256, 0, stream>>>((const float4*)enc, (const float4*)fq,
                                    (const float4*)wq_w, (const float4*)wk_w,
                                    (const float4*)wv_w, (const float4*)wo_w,
                                    enc16, fq16, wq16, wk16, wv16, wo16);

  const float qscale = 0.125f * 1.44269504088896340736f;
  gemm256_fused<<<576, 512, 0, stream>>>(enc16, fq16, wk16, wq16, wk_b, wv_b, wq_b,
                                         Kw, Vtw, Qw, Vsuf, dlen, elen, qscale);
  vsuffix<<<128, 64, 0, stream>>>(Vsuf);

  attn_fwd<<<dim3(8, 8, 16), 256, 0, stream>>>(Qw, Kw, Vtw, Vsuf, dlen, elen, attw);

  oproj<<<dim3(32, 8), 256, 0, stream>>>(attw, wo16, wo_b, (float*)d_out, 4096, 1024, 1024);
}

// Round 18
// 195.271 us; speedup vs baseline: 1.0118x; 1.0118x over previous
//
#include <hip/hip_runtime.h>

typedef __attribute__((ext_vector_type(4))) float f32x4;
typedef __attribute__((ext_vector_type(8))) short s16x8;

__device__ __forceinline__ ushort f2bf(float f) {
  unsigned u = __float_as_uint(f);
  return (ushort)((u + 0x7fffu + ((u >> 16) & 1u)) >> 16);
}

// ---------------- merged f32 -> bf16 conversion (enc, fq, 4 weights) ----------
__global__ __launch_bounds__(256) void cvt_all(
    const float4* __restrict__ enc, const float4* __restrict__ fq,
    const float4* __restrict__ wq, const float4* __restrict__ wk,
    const float4* __restrict__ wv, const float4* __restrict__ wo,
    ushort* __restrict__ enc16, ushort* __restrict__ fq16,
    ushort* __restrict__ wq16, ushort* __restrict__ wk16,
    ushort* __restrict__ wv16, ushort* __restrict__ wo16) {
  const int stride = gridDim.x * 256;
  for (int i = blockIdx.x * 256 + threadIdx.x; i < 6291456; i += stride) {
    const float4* src;
    ushort* dst;
    int k;
    if (i < 4194304) {
      src = enc; dst = enc16; k = i;
    } else if (i < 5242880) {
      src = fq; dst = fq16; k = i - 4194304;
    } else {
      const int j = i - 5242880, sel = j >> 18;
      k = j & 262143;
      src = sel == 0 ? wq : sel == 1 ? wk : sel == 2 ? wv : wo;
      dst = sel == 0 ? wq16 : sel == 1 ? wk16 : sel == 2 ? wv16 : wo16;
    }
    float4 v = src[k];
    uint2 o;
    o.x = (unsigned)f2bf(v.x) | ((unsigned)f2bf(v.y) << 16);
    o.y = (unsigned)f2bf(v.z) | ((unsigned)f2bf(v.w) << 16);
    *(uint2*)(dst + (size_t)k * 4) = o;
  }
}

__device__ __forceinline__ void gload_lds16(const void* g, void* l) {
  __builtin_amdgcn_global_load_lds((const __attribute__((address_space(1))) void*)g,
                                   (__attribute__((address_space(3))) void*)l, 16, 0, 0);
}

// ====== fused K+V+Q projections: 256x256 tile, 8-wave, 8-phase (R8/R16) ======
__global__ __launch_bounds__(512, 1) void gemm256_fused(
    const ushort* __restrict__ enc16, const ushort* __restrict__ fq16,
    const ushort* __restrict__ Bkv, const ushort* __restrict__ Bq,
    const float* __restrict__ wk_b, const float* __restrict__ wv_b,
    const float* __restrict__ wq_b,
    ushort* __restrict__ Ko, ushort* __restrict__ Vt, ushort* __restrict__ Qo,
    float* __restrict__ Tsum, const int* __restrict__ dlen,
    const int* __restrict__ elen, float qscale) {
  __shared__ char lds[131072];  // A: 2dbuf x 2half x 16KB @0 ; B same @64KB
  const int tid = threadIdx.x;
  const int lane = tid & 63, wid = tid >> 6;
  const int g = lane >> 4, r = lane & 15;
  const int wm = wid >> 2, wn = wid & 3;
  const int bid = blockIdx.x;

  const ushort* Amat;
  const ushort* Bmat;
  int m0, n0, role;  // 0=K, 1=V, 2=Q
  if (bid < 512) {
    const int xcd = bid & 7, inner = bid >> 3;
    m0 = (xcd * 8 + (inner & 7)) * 256;  // XCD owns 8 consecutive m-tiles (A reuse)
    n0 = (inner >> 3) * 256;
    Amat = enc16;
    Bmat = Bkv;
    if (n0 < 1024) {
      role = 0;
      if ((m0 & 2047) >= elen[m0 >> 11]) return;  // dead K rows
    } else {
      role = 1;  // V always computed (Tsum needs all tiles)
    }
  } else {
    const int q = bid - 512;
    m0 = (q & 15) * 256;
    n0 = (q >> 4) * 256;
    Amat = fq16;
    Bmat = Bq;
    role = 2;
    if ((m0 & 511) >= dlen[m0 >> 9]) return;  // dead Q rows
  }
  const size_t rowb = 2048;  // K=1024 bf16

  // staging source: row = srow (+64 per second load, +128 per half), col pre-XORed
  const int srow = tid >> 3;
  const int scb = (((tid & 7) ^ (srow & 7)) << 4);
  const char* Asrc = (const char*)Amat + (size_t)(m0 + srow) * rowb + scb;
  const char* Bsrc = (const char*)Bmat + (size_t)(n0 + srow) * rowb + scb;

  auto sAh = [&](int kt, int h) {
    char* d0 = lds + (kt & 1) * 32768 + h * 16384 + tid * 16;
    const char* s0 = Asrc + (size_t)(h * 128) * rowb + (size_t)kt * 128;
    gload_lds16(s0, d0);
    gload_lds16(s0 + (size_t)64 * rowb, d0 + 8192);
  };
  auto sBh = [&](int kt, int h) {
    char* d0 = lds + 65536 + (kt & 1) * 32768 + h * 16384 + tid * 16;
    const char* s0 = Bsrc + (size_t)(h * 128) * rowb + (size_t)kt * 128;
    gload_lds16(s0, d0);
    gload_lds16(s0 + (size_t)64 * rowb, d0 + 8192);
  };

  const int cb0 = (g * 16) ^ ((r & 7) << 4);
  const int cb1 = (64 + g * 16) ^ ((r & 7) << 4);

  f32x4 acc[8][4] = {};

  // prologue: kt0 A+B, kt1 B (kt1 A staged in iter0 p1,p2)
  sAh(0, 0); sAh(0, 1); sBh(0, 0); sBh(0, 1); sBh(1, 0); sBh(1, 1);
  asm volatile("s_waitcnt vmcnt(4)" ::: "memory");
  __builtin_amdgcn_s_barrier();

#define MFMA_(a, b, c) __builtin_amdgcn_mfma_f32_16x16x32_bf16(a, b, c, 0, 0, 0)
#define PH(AB, Q, STAGE, WAIT)                                                 \
  {                                                                            \
    s16x8 aq0 = *(const s16x8*)(AB + (2 * (Q)) * 2048 + cb0);                  \
    s16x8 aq1 = *(const s16x8*)(AB + (2 * (Q)) * 2048 + cb1);                  \
    s16x8 aq2 = *(const s16x8*)(AB + (2 * (Q) + 1) * 2048 + cb0);              \
    s16x8 aq3 = *(const s16x8*)(AB + (2 * (Q) + 1) * 2048 + cb1);              \
    STAGE;                                                                     \
    __builtin_amdgcn_s_barrier();                                              \
    asm volatile("s_waitcnt lgkmcnt(0)" ::: "memory");                         \
    __builtin_amdgcn_sched_barrier(0);                                         \
    __builtin_amdgcn_s_setprio(1);                                             \
    _Pragma("unroll") for (int ni = 0; ni < 4; ++ni)                           \
        acc[2 * (Q)][ni] = MFMA_(aq0, bfr[ni][0], acc[2 * (Q)][ni]);           \
    _Pragma("unroll") for (int ni = 0; ni < 4; ++ni)                           \
        acc[2 * (Q) + 1][ni] = MFMA_(aq2, bfr[ni][0], acc[2 * (Q) + 1][ni]);   \
    _Pragma("unroll") for (int ni = 0; ni < 4; ++ni)                           \
        acc[2 * (Q)][ni] = MFMA_(aq1, bfr[ni][1], acc[2 * (Q)][ni]);           \
    _Pragma("unroll") for (int ni = 0; ni < 4; ++ni)                           \
        acc[2 * (Q) + 1][ni] = MFMA_(aq3, bfr[ni][1], acc[2 * (Q) + 1][ni]);   \
    __builtin_amdgcn_s_setprio(0);                                             \
    WAIT;                                                                      \
    __builtin_amdgcn_s_barrier();                                              \
  }
#define LOADB(BB)                                                              \
  _Pragma("unroll") for (int ni = 0; ni < 4; ++ni) {                           \
    bfr[ni][0] = *(const s16x8*)(BB + ni * 2048 + cb0);                        \
    bfr[ni][1] = *(const s16x8*)(BB + ni * 2048 + cb1);                        \
  }

  const int NIT = 8;  // K=1024: 8 super-iters (2 K-tiles each)
  const char* AbB = lds + wm * 16384 + r * 128;
  const char* BbB = lds + 65536 + (wn >> 1) * 16384 + (wn & 1) * 8192 + r * 128;

  for (int it = 0; it < NIT; ++it) {
    const bool st = (it + 1 < NIT);
    const int k1 = 2 * it + 1, k2 = 2 * it + 2, k3 = 2 * it + 3;
    s16x8 bfr[4][2];
    // ---- half 0: kt = 2it from dbuf0
    LOADB(BbB);
    PH(AbB, 0, sAh(k1, 0), );
    PH(AbB, 1, sAh(k1, 1), );
    PH(AbB, 2, if (st) sBh(k2, 0), );
    PH(AbB, 3, if (st) sBh(k2, 1),
       if (st) { asm volatile("s_waitcnt vmcnt(4)" ::: "memory"); } else {
         asm volatile("s_waitcnt vmcnt(0)" ::: "memory");
       });
    // ---- half 1: kt = 2it+1 from dbuf1
    const char* Ab1 = AbB + 32768;
    const char* Bb1 = BbB + 32768;
    LOADB(Bb1);
    PH(Ab1, 0, if (st) sAh(k2, 0), );
    PH(Ab1, 1, if (st) sAh(k2, 1), );
    PH(Ab1, 2, if (st) sBh(k3, 0), );
    PH(Ab1, 3, if (st) sBh(k3, 1),
       if (st) { asm volatile("s_waitcnt vmcnt(4)" ::: "memory"); });
  }
#undef PH
#undef LOADB
#undef MFMA_

  // ---- epilogue: acc row = m0 + wm*128 + i*16 + g*4 + j, col = n0 + wn*64 + ni*16 + r
  if (role != 1) {
    ushort* C = (role == 2) ? Qo : Ko;
    const float* bias0 = (role == 2) ? wq_b : wk_b;
    const float sc = (role == 2) ? qscale : 1.0f;
    // bounce to LDS [row 256][col 256] bf16, 16B-slot XOR ((row>>2)&7)<<4
#pragma unroll
    for (int ni = 0; ni < 4; ++ni) {
      const int col = wn * 64 + ni * 16 + r;
      const float bv = bias0[n0 + col];
#pragma unroll
      for (int i = 0; i < 8; ++i)
#pragma unroll
        for (int j = 0; j < 4; ++j) {
          const int row = wm * 128 + i * 16 + g * 4 + j;
          *(ushort*)(lds + ((row * 512 + col * 2) ^ (((row >> 2) & 7) << 4))) =
              f2bf((acc[i][ni][j] + bv) * sc);
        }
    }
    __syncthreads();
    const int c = tid & 31, r0 = tid >> 5;
#pragma unroll
    for (int u = 0; u < 16; ++u) {
      const int row = u * 16 + r0;
      s16x8 v = *(const s16x8*)(lds + ((row * 512 + c * 16) ^ (((row >> 2) & 7) << 4)));
      *(s16x8*)(C + (size_t)(m0 + row) * 1024 + n0 + c * 8) = v;
    }
  } else {
    const int nv0 = n0 - 1024;
    const int bb = m0 >> 11, tt0 = m0 & 2047;
    // per-64-tt-tile column sums (wave-unique (q, nv): q = wm*2 + qq)
#pragma unroll
    for (int ni = 0; ni < 4; ++ni) {
      const int nv = nv0 + wn * 64 + ni * 16 + r;
      const float bv = wv_b[nv];
#pragma unroll
      for (int qq = 0; qq < 2; ++qq) {
        float s = 0.0f;
#pragma unroll
        for (int ii = 0; ii < 4; ++ii)
#pragma unroll
          for (int j = 0; j < 4; ++j) s += acc[qq * 4 + ii][ni][j];
        s += __shfl_xor(s, 16);
        s += __shfl_xor(s, 32);
        if (g == 0) {
          const int gt = (m0 + (wm * 2 + qq) * 64) >> 6;
          Tsum[((size_t)((gt >> 5) * 16 + (nv >> 6)) * 33 + (gt & 31)) * 64 + (nv & 63)] =
              s + 64.0f * bv;
        }
      }
    }
    // bounce to LDS [nv-local 256][tt-local 256] bf16, XOR ((row&7)<<4)
#pragma unroll
    for (int ni = 0; ni < 4; ++ni) {
      const int rowl = wn * 64 + ni * 16 + r;
      const float bv = wv_b[nv0 + rowl];
#pragma unroll
      for (int i = 0; i < 8; ++i)
#pragma unroll
        for (int j = 0; j < 4; ++j) {
          const int coll = wm * 128 + i * 16 + g * 4 + j;
          *(ushort*)(lds + ((rowl * 512 + coll * 2) ^ ((rowl & 7) << 4))) =
              f2bf(acc[i][ni][j] + bv);
        }
    }
    __syncthreads();
    const int c = tid & 31, r0 = tid >> 5;
#pragma unroll
    for (int u = 0; u < 16; ++u) {
      const int row = u * 16 + r0;
      s16x8 v = *(const s16x8*)(lds + ((row * 512 + c * 16) ^ ((row & 7) << 4)));
      *(s16x8*)(Vt + ((size_t)bb * 1024 + nv0 + row) * 2048 + tt0 + c * 8) = v;
    }
  }
}

// ---------------- 128x128 GEMM (O projection, f32 out) ----------------
__global__ __launch_bounds__(256) void oproj(const ushort* __restrict__ A,
                                             const ushort* __restrict__ B,
                                             const float* __restrict__ bias,
                                             float* __restrict__ C, int M, int N, int K) {
  __shared__ ushort As[128 * 32];
  __shared__ ushort Bs[128 * 32];
  const int tid = threadIdx.x;
  const int lane = tid & 63, w = tid >> 6;
  const int g = lane >> 4, r = lane & 15;
  const int m0 = blockIdx.x * 128, n0 = blockIdx.y * 128;
  const int wm = (w >> 1) * 64, wn = (w & 1) * 64;

  const int srow = tid >> 2;
  const int scb = (tid & 3) * 16;
  const char* Ag = (const char*)(A + (size_t)(m0 + srow) * K) + scb;
  const char* Bg = (const char*)(B + (size_t)(n0 + srow) * K) + scb;
  char* AsB = (char*)As + (tid & 192) * 16;
  char* BsB = (char*)Bs + (tid & 192) * 16;
  const size_t rowskip = (size_t)64 * K * sizeof(ushort);

  f32x4 acc[4][4] = {};

  for (int k0 = 0; k0 < K; k0 += 32) {
    gload_lds16(Ag + (size_t)k0 * 2, AsB);
    gload_lds16(Ag + rowskip + (size_t)k0 * 2, AsB + 4096);
    gload_lds16(Bg + (size_t)k0 * 2, BsB);
    gload_lds16(Bg + rowskip + (size_t)k0 * 2, BsB + 4096);
    __syncthreads();
    s16x8 af[4], bf[4];
#pragma unroll
    for (int i = 0; i < 4; ++i) af[i] = *(const s16x8*)&As[(wm + i * 16 + r) * 32 + g * 8];
#pragma unroll
    for (int i = 0; i < 4; ++i) bf[i] = *(const s16x8*)&Bs[(wn + i * 16 + r) * 32 + g * 8];
#pragma unroll
    for (int mi = 0; mi < 4; ++mi)
#pragma unroll
      for (int ni = 0; ni < 4; ++ni)
        acc[mi][ni] =
            __builtin_amdgcn_mfma_f32_16x16x32_bf16(af[mi], bf[ni], acc[mi][ni], 0, 0, 0);
    __syncthreads();
  }

#pragma unroll
  for (int ni = 0; ni < 4; ++ni) {
    const int n = n0 + wn + ni * 16 + r;
    const float bv = bias[n];
#pragma unroll
    for (int mi = 0; mi < 4; ++mi) {
      const int mb = m0 + wm + mi * 16 + g * 4;
#pragma unroll
      for (int j = 0; j < 4; ++j)
        C[(size_t)(mb + j) * N + n] = acc[mi][ni][j] + bv;
    }
  }
}

// suffix-sum over tiles: Vsuf[b][h][t][d] = sum_{t'>=t} tilesum  (t=0..32, [32]=0)
__global__ __launch_bounds__(64) void vsuffix(float* __restrict__ T) {
  const int bh = blockIdx.x;
  const int d = threadIdx.x;
  float* p = T + (size_t)bh * 33 * 64 + d;
  float run = 0.0f;
  p[32 * 64] = 0.0f;
  for (int t = 31; t >= 0; --t) {
    run += p[t * 64];
    p[t * 64] = run;
  }
}

// ---------------- fused masked attention (R14 + T5 setprio) ------------------
__device__ __forceinline__ ushort* swz(ushort* base, int row, int colb) {
  return (ushort*)((char*)base + row * 128 + (colb ^ ((row & 7) << 4)));
}

__global__ __launch_bounds__(256) void attn_fwd(
    const ushort* __restrict__ Q, const ushort* __restrict__ Km,
    const ushort* __restrict__ Vt, const float* __restrict__ Vsuf,
    const int* __restrict__ dlen, const int* __restrict__ elen,
    ushort* __restrict__ Oatt) {
  const int tid = threadIdx.x;
  const int lane = tid & 63, w = tid >> 6;
  const int g = lane >> 4, r = lane & 15;
  const int qt = blockIdx.x, b = blockIdx.y, h = blockIdx.z;
  const int dl = dlen[b], el = elen[b];
  const float* VS = Vsuf + (size_t)(b * 16 + h) * 33 * 64;

  if (qt * 64 >= dl) {
    const int qrow = qt * 64 + w * 16 + g * 4;
#pragma unroll
    for (int dt = 0; dt < 4; ++dt) {
      const ushort hv = f2bf(VS[dt * 16 + r] * (1.0f / 2048.0f));
#pragma unroll
      for (int j = 0; j < 4; ++j)
        Oatt[(size_t)(b * 512 + qrow + j) * 1024 + h * 64 + dt * 16 + r] = hv;
    }
    return;
  }

  __shared__ ushort Ks[64 * 64];
  __shared__ ushort Vs[64 * 64];
  __shared__ ushort Ps[4 * 16 * 64];
  ushort* PsW = Ps + w * 16 * 64;
  const int qbase = qt * 64 + w * 16;

  s16x8 qf[2];
  {
    const ushort* qp = Q + (size_t)(b * 512 + qbase + r) * 1024 + h * 64 + g * 8;
    qf[0] = *(const s16x8*)qp;
    qf[1] = *(const s16x8*)(qp + 32);
  }

  f32x4 o[4] = {};
  float lrow[4] = {0.0f, 0.0f, 0.0f, 0.0f};
  bool qok[4];
#pragma unroll
  for (int j = 0; j < 4; ++j) qok[j] = (qbase + g * 4 + j) < dl;

  const int sr = tid >> 3;
  const int sc8 = (tid & 7) * 8;
  const int scb = sc8 * 2;
  const ushort* Kg = Km + (size_t)(b * 2048 + sr) * 1024 + h * 64 + sc8;
  const ushort* Vg = Vt + ((size_t)b * 1024 + h * 64 + sr) * 2048 + sc8;

  const int t_last = (el - 1) >> 6;

  s16x8 pk0, pk1, pv0, pv1;
  {
    pk0 = *(const s16x8*)(Kg);
    pk1 = *(const s16x8*)(Kg + (size_t)32 * 1024);
    pv0 = *(const s16x8*)(Vg);
    pv1 = *(const s16x8*)(Vg + (size_t)32 * 2048);
  }

  for (int t = 0; t <= t_last; ++t) {
    *(s16x8*)swz(Ks, sr, scb) = pk0;
    *(s16x8*)swz(Ks, sr + 32, scb) = pk1;
    *(s16x8*)swz(Vs, sr, scb) = pv0;
    *(s16x8*)swz(Vs, sr + 32, scb) = pv1;
    __syncthreads();

    if (t < t_last) {
      const int kv0 = (t + 1) * 64;
      pk0 = *(const s16x8*)(Kg + (size_t)kv0 * 1024);
      pk1 = *(const s16x8*)(Kg + (size_t)(kv0 + 32) * 1024);
      pv0 = *(const s16x8*)(Vg + kv0);
      pv1 = *(const s16x8*)(Vg + (size_t)32 * 2048 + kv0);
    }

    const int kv0 = t * 64;
    float p[4][4];
#pragma unroll
    for (int nt = 0; nt < 4; ++nt) {
      f32x4 s = {};
      s16x8 kf0 = *(const s16x8*)swz(Ks, nt * 16 + r, g * 16);
      s16x8 kf1 = *(const s16x8*)swz(Ks, nt * 16 + r, 64 + g * 16);
      __builtin_amdgcn_s_setprio(1);
      s = __builtin_amdgcn_mfma_f32_16x16x32_bf16(qf[0], kf0, s, 0, 0, 0);
      s = __builtin_amdgcn_mfma_f32_16x16x32_bf16(qf[1], kf1, s, 0, 0, 0);
      __builtin_amdgcn_s_setprio(0);
      const bool kok = (kv0 + nt * 16 + r) < el;
#pragma unroll
      for (int j = 0; j < 4; ++j) {
        const float pe = __builtin_amdgcn_exp2f(s[j]);
        p[nt][j] = (kok && qok[j]) ? pe : 1.0f;
      }
    }
#pragma unroll
    for (int nt = 0; nt < 4; ++nt)
#pragma unroll
      for (int j = 0; j < 4; ++j) lrow[j] += p[nt][j];

#pragma unroll
    for (int nt = 0; nt < 4; ++nt) {
#pragma unroll
      for (int jp = 0; jp < 4; jp += 2) {
        unsigned pk;
        asm("v_cvt_pk_bf16_f32 %0, %1, %2" : "=v"(pk) : "v"(p[nt][jp]), "v"(p[nt][jp + 1]));
        *swz(PsW, g * 4 + jp, (nt * 16 + r) * 2) = (ushort)pk;
        *swz(PsW, g * 4 + jp + 1, (nt * 16 + r) * 2) = (ushort)(pk >> 16);
      }
    }

#pragma unroll
    for (int kc = 0; kc < 2; ++kc) {
      s16x8 pf = *(const s16x8*)swz(PsW, r, kc * 64 + g * 16);
      __builtin_amdgcn_s_setprio(1);
#pragma unroll
      for (int dt = 0; dt < 4; ++dt) {
        s16x8 vf = *(const s16x8*)swz(Vs, dt * 16 + r, kc * 64 + g * 16);
        o[dt] = __builtin_amdgcn_mfma_f32_16x16x32_bf16(pf, vf, o[dt], 0, 0, 0);
      }
      __builtin_amdgcn_s_setprio(0);
    }
    __syncthreads();
  }

  const float tailcnt = (float)(2048 - (t_last + 1) * 64);
  const float* VT = VS + (t_last + 1) * 64;
#pragma unroll
  for (int dt = 0; dt < 4; ++dt) {
    const float tv = VT[dt * 16 + r];
#pragma unroll
    for (int j = 0; j < 4; ++j) o[dt][j] += tv;
  }

  float inv[4];
#pragma unroll
  for (int j = 0; j < 4; ++j) {
    float s = lrow[j];
    s += __shfl_xor(s, 1);
    s += __shfl_xor(s, 2);
    s += __shfl_xor(s, 4);
    s += __shfl_xor(s, 8);
    inv[j] = 1.0f / (s + tailcnt);
  }
#pragma unroll
  for (int dt = 0; dt < 4; ++dt)
#pragma unroll
    for (int j = 0; j < 4; ++j)
      Oatt[(size_t)(b * 512 + qbase + g * 4 + j) * 1024 + h * 64 + dt * 16 + r] =
          f2bf(o[dt][j] * inv[j]);
}

// ---------------- launch ----------------
extern "C" void kernel_launch(void* const* d_in, const int* in_sizes, int n_in,
                              void* d_out, int out_size, void* d_ws, size_t ws_size,
                              hipStream_t stream) {
  const float* enc  = (const float*)d_in[0];
  const float* fq   = (const float*)d_in[1];
  const int* dlen   = (const int*)d_in[2];
  const int* elen   = (const int*)d_in[3];
  const float* wq_w = (const float*)d_in[4];
  const float* wq_b = (const float*)d_in[5];
  const float* wk_w = (const float*)d_in[6];
  const float* wk_b = (const float*)d_in[7];
  const float* wv_w = (const float*)d_in[8];
  const float* wv_b = (const float*)d_in[9];
  const float* wo_w = (const float*)d_in[10];
  const float* wo_b = (const float*)d_in[11];

  char* ws = (char*)d_ws;  // all within 128MB; attw aliases fq16 (dead by attn time)
  ushort* enc16 = (ushort*)(ws + 0);           // 32 MB
  ushort* fq16  = (ushort*)(ws + 33554432);    // 8 MB
  ushort* attw  = (ushort*)(ws + 33554432);    // alias of fq16
  ushort* wq16  = (ushort*)(ws + 41943040);    // 2 MB
  ushort* wk16  = (ushort*)(ws + 44040192);    // 2 MB  | adjacent: [wk;wv] = B concat
  ushort* wv16  = (ushort*)(ws + 46137344);    // 2 MB  |
  ushort* wo16  = (ushort*)(ws + 48234496);    // 2 MB
  float*  Vsuf  = (float*)(ws + 50331648);     // ~1.06 MB (Tsum/Vsuf)
  ushort* Qw    = (ushort*)(ws + 52428800);    // 8 MB
  ushort* Kw    = (ushort*)(ws + 60817408);    // 32 MB
  ushort* Vtw   = (ushort*)(ws + 94371840);    // 32 MB, ends 126877696 < 128MB

  cvt_all<<<4096, 256, 0, stream>>>((const float4*)enc, (const float4*)fq,
                                    (const float4*)wq_w, (const float4*)wk_w,
                                    (const float4*)wv_w, (const float4*)wo_w,
                                    enc16, fq16, wq16, wk16, wv16, wo16);

  const float qscale = 0.125f * 1.44269504088896340736f;
  gemm256_fused<<<576, 512, 0, stream>>>(enc16, fq16, wk16, wq16, wk_b, wv_b, wq_b,
                                         Kw, Vtw, Qw, Vsuf, dlen, elen, qscale);
  vsuffix<<<128, 64, 0, stream>>>(Vsuf);

  attn_fwd<<<dim3(8, 8, 16), 256, 0, stream>>>(Qw, Kw, Vtw, Vsuf, dlen, elen, attw);

  oproj<<<dim3(32, 8), 256, 0, stream>>>(attw, wo16, wo_b, (float*)d_out, 4096, 1024, 1024);
}

// Round 19
// 180.966 us; speedup vs baseline: 1.0918x; 1.0790x over previous
//
#include <hip/hip_runtime.h>

typedef __attribute__((ext_vector_type(4))) float f32x4;
typedef __attribute__((ext_vector_type(8))) short s16x8;

__device__ __forceinline__ ushort f2bf(float f) {
  unsigned u = __float_as_uint(f);
  return (ushort)((u + 0x7fffu + ((u >> 16) & 1u)) >> 16);
}

// ---------------- merged f32 -> bf16 conversion (enc, fq, 4 weights) ----------
__global__ __launch_bounds__(256) void cvt_all(
    const float4* __restrict__ enc, const float4* __restrict__ fq,
    const float4* __restrict__ wq, const float4* __restrict__ wk,
    const float4* __restrict__ wv, const float4* __restrict__ wo,
    ushort* __restrict__ enc16, ushort* __restrict__ fq16,
    ushort* __restrict__ wq16, ushort* __restrict__ wk16,
    ushort* __restrict__ wv16, ushort* __restrict__ wo16) {
  const int stride = gridDim.x * 256;
  for (int i = blockIdx.x * 256 + threadIdx.x; i < 6291456; i += stride) {
    const float4* src;
    ushort* dst;
    int k;
    if (i < 4194304) {
      src = enc; dst = enc16; k = i;
    } else if (i < 5242880) {
      src = fq; dst = fq16; k = i - 4194304;
    } else {
      const int j = i - 5242880, sel = j >> 18;
      k = j & 262143;
      src = sel == 0 ? wq : sel == 1 ? wk : sel == 2 ? wv : wo;
      dst = sel == 0 ? wq16 : sel == 1 ? wk16 : sel == 2 ? wv16 : wo16;
    }
    float4 v = src[k];
    uint2 o;
    o.x = (unsigned)f2bf(v.x) | ((unsigned)f2bf(v.y) << 16);
    o.y = (unsigned)f2bf(v.z) | ((unsigned)f2bf(v.w) << 16);
    *(uint2*)(dst + (size_t)k * 4) = o;
  }
}

__device__ __forceinline__ void gload_lds16(const void* g, void* l) {
  __builtin_amdgcn_global_load_lds((const __attribute__((address_space(1))) void*)g,
                                   (__attribute__((address_space(3))) void*)l, 16, 0, 0);
}

// ====== fused K+V+Q projections: 256x256 tile, 8-wave, 8-phase (R8/R16) ======
__global__ __launch_bounds__(512, 1) void gemm256_fused(
    const ushort* __restrict__ enc16, const ushort* __restrict__ fq16,
    const ushort* __restrict__ Bkv, const ushort* __restrict__ Bq,
    const float* __restrict__ wk_b, const float* __restrict__ wv_b,
    const float* __restrict__ wq_b,
    ushort* __restrict__ Ko, ushort* __restrict__ Vt, ushort* __restrict__ Qo,
    float* __restrict__ Tsum, const int* __restrict__ dlen,
    const int* __restrict__ elen, float qscale) {
  __shared__ char lds[131072];  // A: 2dbuf x 2half x 16KB @0 ; B same @64KB
  const int tid = threadIdx.x;
  const int lane = tid & 63, wid = tid >> 6;
  const int g = lane >> 4, r = lane & 15;
  const int wm = wid >> 2, wn = wid & 3;
  const int bid = blockIdx.x;

  const ushort* Amat;
  const ushort* Bmat;
  int m0, n0, role;  // 0=K, 1=V, 2=Q
  if (bid < 512) {
    const int xcd = bid & 7, inner = bid >> 3;
    m0 = (xcd * 8 + (inner & 7)) * 256;  // XCD owns 8 consecutive m-tiles (A reuse)
    n0 = (inner >> 3) * 256;
    Amat = enc16;
    Bmat = Bkv;
    if (n0 < 1024) {
      role = 0;
      if ((m0 & 2047) >= elen[m0 >> 11]) return;  // dead K rows
    } else {
      role = 1;  // V always computed (Tsum needs all tiles)
    }
  } else {
    const int q = bid - 512;
    m0 = (q & 15) * 256;
    n0 = (q >> 4) * 256;
    Amat = fq16;
    Bmat = Bq;
    role = 2;
    if ((m0 & 511) >= dlen[m0 >> 9]) return;  // dead Q rows
  }
  const size_t rowb = 2048;  // K=1024 bf16

  // staging source: row = srow (+64 per second load, +128 per half), col pre-XORed
  const int srow = tid >> 3;
  const int scb = (((tid & 7) ^ (srow & 7)) << 4);
  const char* Asrc = (const char*)Amat + (size_t)(m0 + srow) * rowb + scb;
  const char* Bsrc = (const char*)Bmat + (size_t)(n0 + srow) * rowb + scb;

  auto sAh = [&](int kt, int h) {
    char* d0 = lds + (kt & 1) * 32768 + h * 16384 + tid * 16;
    const char* s0 = Asrc + (size_t)(h * 128) * rowb + (size_t)kt * 128;
    gload_lds16(s0, d0);
    gload_lds16(s0 + (size_t)64 * rowb, d0 + 8192);
  };
  auto sBh = [&](int kt, int h) {
    char* d0 = lds + 65536 + (kt & 1) * 32768 + h * 16384 + tid * 16;
    const char* s0 = Bsrc + (size_t)(h * 128) * rowb + (size_t)kt * 128;
    gload_lds16(s0, d0);
    gload_lds16(s0 + (size_t)64 * rowb, d0 + 8192);
  };

  const int cb0 = (g * 16) ^ ((r & 7) << 4);
  const int cb1 = (64 + g * 16) ^ ((r & 7) << 4);

  f32x4 acc[8][4] = {};

  // prologue: kt0 A+B, kt1 B (kt1 A staged in iter0 p1,p2)
  sAh(0, 0); sAh(0, 1); sBh(0, 0); sBh(0, 1); sBh(1, 0); sBh(1, 1);
  asm volatile("s_waitcnt vmcnt(4)" ::: "memory");
  __builtin_amdgcn_s_barrier();

#define MFMA_(a, b, c) __builtin_amdgcn_mfma_f32_16x16x32_bf16(a, b, c, 0, 0, 0)
#define PH(AB, Q, STAGE, WAIT)                                                 \
  {                                                                            \
    s16x8 aq0 = *(const s16x8*)(AB + (2 * (Q)) * 2048 + cb0);                  \
    s16x8 aq1 = *(const s16x8*)(AB + (2 * (Q)) * 2048 + cb1);                  \
    s16x8 aq2 = *(const s16x8*)(AB + (2 * (Q) + 1) * 2048 + cb0);              \
    s16x8 aq3 = *(const s16x8*)(AB + (2 * (Q) + 1) * 2048 + cb1);              \
    STAGE;                                                                     \
    __builtin_amdgcn_s_barrier();                                              \
    asm volatile("s_waitcnt lgkmcnt(0)" ::: "memory");                         \
    __builtin_amdgcn_sched_barrier(0);                                         \
    __builtin_amdgcn_s_setprio(1);                                             \
    _Pragma("unroll") for (int ni = 0; ni < 4; ++ni)                           \
        acc[2 * (Q)][ni] = MFMA_(aq0, bfr[ni][0], acc[2 * (Q)][ni]);           \
    _Pragma("unroll") for (int ni = 0; ni < 4; ++ni)                           \
        acc[2 * (Q) + 1][ni] = MFMA_(aq2, bfr[ni][0], acc[2 * (Q) + 1][ni]);   \
    _Pragma("unroll") for (int ni = 0; ni < 4; ++ni)                           \
        acc[2 * (Q)][ni] = MFMA_(aq1, bfr[ni][1], acc[2 * (Q)][ni]);           \
    _Pragma("unroll") for (int ni = 0; ni < 4; ++ni)                           \
        acc[2 * (Q) + 1][ni] = MFMA_(aq3, bfr[ni][1], acc[2 * (Q) + 1][ni]);   \
    __builtin_amdgcn_s_setprio(0);                                             \
    WAIT;                                                                      \
    __builtin_amdgcn_s_barrier();                                              \
  }
#define LOADB(BB)                                                              \
  _Pragma("unroll") for (int ni = 0; ni < 4; ++ni) {                           \
    bfr[ni][0] = *(const s16x8*)(BB + ni * 2048 + cb0);                        \
    bfr[ni][1] = *(const s16x8*)(BB + ni * 2048 + cb1);                        \
  }

  const int NIT = 8;  // K=1024: 8 super-iters (2 K-tiles each)
  const char* AbB = lds + wm * 16384 + r * 128;
  const char* BbB = lds + 65536 + (wn >> 1) * 16384 + (wn & 1) * 8192 + r * 128;

  for (int it = 0; it < NIT; ++it) {
    const bool st = (it + 1 < NIT);
    const int k1 = 2 * it + 1, k2 = 2 * it + 2, k3 = 2 * it + 3;
    s16x8 bfr[4][2];
    // ---- half 0: kt = 2it from dbuf0
    LOADB(BbB);
    PH(AbB, 0, sAh(k1, 0), );
    PH(AbB, 1, sAh(k1, 1), );
    PH(AbB, 2, if (st) sBh(k2, 0), );
    PH(AbB, 3, if (st) sBh(k2, 1),
       if (st) { asm volatile("s_waitcnt vmcnt(4)" ::: "memory"); } else {
         asm volatile("s_waitcnt vmcnt(0)" ::: "memory");
       });
    // ---- half 1: kt = 2it+1 from dbuf1
    const char* Ab1 = AbB + 32768;
    const char* Bb1 = BbB + 32768;
    LOADB(Bb1);
    PH(Ab1, 0, if (st) sAh(k2, 0), );
    PH(Ab1, 1, if (st) sAh(k2, 1), );
    PH(Ab1, 2, if (st) sBh(k3, 0), );
    PH(Ab1, 3, if (st) sBh(k3, 1),
       if (st) { asm volatile("s_waitcnt vmcnt(4)" ::: "memory"); });
  }
#undef PH
#undef LOADB
#undef MFMA_

  // ---- epilogue: acc row = m0 + wm*128 + i*16 + g*4 + j, col = n0 + wn*64 + ni*16 + r
  if (role != 1) {
    ushort* C = (role == 2) ? Qo : Ko;
    const float* bias0 = (role == 2) ? wq_b : wk_b;
    const float sc = (role == 2) ? qscale : 1.0f;
    // bounce to LDS [row 256][col 256] bf16, 16B-slot XOR ((row>>2)&7)<<4
#pragma unroll
    for (int ni = 0; ni < 4; ++ni) {
      const int col = wn * 64 + ni * 16 + r;
      const float bv = bias0[n0 + col];
#pragma unroll
      for (int i = 0; i < 8; ++i)
#pragma unroll
        for (int j = 0; j < 4; ++j) {
          const int row = wm * 128 + i * 16 + g * 4 + j;
          *(ushort*)(lds + ((row * 512 + col * 2) ^ (((row >> 2) & 7) << 4))) =
              f2bf((acc[i][ni][j] + bv) * sc);
        }
    }
    __syncthreads();
    const int c = tid & 31, r0 = tid >> 5;
#pragma unroll
    for (int u = 0; u < 16; ++u) {
      const int row = u * 16 + r0;
      s16x8 v = *(const s16x8*)(lds + ((row * 512 + c * 16) ^ (((row >> 2) & 7) << 4)));
      *(s16x8*)(C + (size_t)(m0 + row) * 1024 + n0 + c * 8) = v;
    }
  } else {
    const int nv0 = n0 - 1024;
    const int bb = m0 >> 11, tt0 = m0 & 2047;
    // per-64-tt-tile column sums (wave-unique (q, nv): q = wm*2 + qq)
#pragma unroll
    for (int ni = 0; ni < 4; ++ni) {
      const int nv = nv0 + wn * 64 + ni * 16 + r;
      const float bv = wv_b[nv];
#pragma unroll
      for (int qq = 0; qq < 2; ++qq) {
        float s = 0.0f;
#pragma unroll
        for (int ii = 0; ii < 4; ++ii)
#pragma unroll
          for (int j = 0; j < 4; ++j) s += acc[qq * 4 + ii][ni][j];
        s += __shfl_xor(s, 16);
        s += __shfl_xor(s, 32);
        if (g == 0) {
          const int gt = (m0 + (wm * 2 + qq) * 64) >> 6;
          Tsum[((size_t)((gt >> 5) * 16 + (nv >> 6)) * 33 + (gt & 31)) * 64 + (nv & 63)] =
              s + 64.0f * bv;
        }
      }
    }
    // bounce to LDS [nv-local 256][tt-local 256] bf16, XOR ((row&7)<<4)
#pragma unroll
    for (int ni = 0; ni < 4; ++ni) {
      const int rowl = wn * 64 + ni * 16 + r;
      const float bv = wv_b[nv0 + rowl];
#pragma unroll
      for (int i = 0; i < 8; ++i)
#pragma unroll
        for (int j = 0; j < 4; ++j) {
          const int coll = wm * 128 + i * 16 + g * 4 + j;
          *(ushort*)(lds + ((rowl * 512 + coll * 2) ^ ((rowl & 7) << 4))) =
              f2bf(acc[i][ni][j] + bv);
        }
    }
    __syncthreads();
    const int c = tid & 31, r0 = tid >> 5;
#pragma unroll
    for (int u = 0; u < 16; ++u) {
      const int row = u * 16 + r0;
      s16x8 v = *(const s16x8*)(lds + ((row * 512 + c * 16) ^ ((row & 7) << 4)));
      *(s16x8*)(Vt + ((size_t)bb * 1024 + nv0 + row) * 2048 + tt0 + c * 8) = v;
    }
  }
}

// ---------------- 128x128 GEMM (O projection, f32 out) ----------------
__global__ __launch_bounds__(256) void oproj(const ushort* __restrict__ A,
                                             const ushort* __restrict__ B,
                                             const float* __restrict__ bias,
                                             float* __restrict__ C, int M, int N, int K) {
  __shared__ ushort As[128 * 32];
  __shared__ ushort Bs[128 * 32];
  const int tid = threadIdx.x;
  const int lane = tid & 63, w = tid >> 6;
  const int g = lane >> 4, r = lane & 15;
  const int m0 = blockIdx.x * 128, n0 = blockIdx.y * 128;
  const int wm = (w >> 1) * 64, wn = (w & 1) * 64;

  const int srow = tid >> 2;
  const int scb = (tid & 3) * 16;
  const char* Ag = (const char*)(A + (size_t)(m0 + srow) * K) + scb;
  const char* Bg = (const char*)(B + (size_t)(n0 + srow) * K) + scb;
  char* AsB = (char*)As + (tid & 192) * 16;
  char* BsB = (char*)Bs + (tid & 192) * 16;
  const size_t rowskip = (size_t)64 * K * sizeof(ushort);

  f32x4 acc[4][4] = {};

  for (int k0 = 0; k0 < K; k0 += 32) {
    gload_lds16(Ag + (size_t)k0 * 2, AsB);
    gload_lds16(Ag + rowskip + (size_t)k0 * 2, AsB + 4096);
    gload_lds16(Bg + (size_t)k0 * 2, BsB);
    gload_lds16(Bg + rowskip + (size_t)k0 * 2, BsB + 4096);
    __syncthreads();
    s16x8 af[4], bf[4];
#pragma unroll
    for (int i = 0; i < 4; ++i) af[i] = *(const s16x8*)&As[(wm + i * 16 + r) * 32 + g * 8];
#pragma unroll
    for (int i = 0; i < 4; ++i) bf[i] = *(const s16x8*)&Bs[(wn + i * 16 + r) * 32 + g * 8];
#pragma unroll
    for (int mi = 0; mi < 4; ++mi)
#pragma unroll
      for (int ni = 0; ni < 4; ++ni)
        acc[mi][ni] =
            __builtin_amdgcn_mfma_f32_16x16x32_bf16(af[mi], bf[ni], acc[mi][ni], 0, 0, 0);
    __syncthreads();
  }

#pragma unroll
  for (int ni = 0; ni < 4; ++ni) {
    const int n = n0 + wn + ni * 16 + r;
    const float bv = bias[n];
#pragma unroll
    for (int mi = 0; mi < 4; ++mi) {
      const int mb = m0 + wm + mi * 16 + g * 4;
#pragma unroll
      for (int j = 0; j < 4; ++j)
        C[(size_t)(mb + j) * N + n] = acc[mi][ni][j] + bv;
    }
  }
}

// suffix-sum over tiles: Vsuf[b][h][t][d] = sum_{t'>=t} tilesum  (t=0..32, [32]=0)
__global__ __launch_bounds__(64) void vsuffix(float* __restrict__ T) {
  const int bh = blockIdx.x;
  const int d = threadIdx.x;
  float* p = T + (size_t)bh * 33 * 64 + d;
  float run = 0.0f;
  p[32 * 64] = 0.0f;
  for (int t = 31; t >= 0; --t) {
    run += p[t * 64];
    p[t * 64] = run;
  }
}

// ---------------- fused masked attention (R18 + XCD-local grid) --------------
// Grid (x = b*16+h = 128, y = qt = 8): linear id = x + 128*y, XCD = x & 7 =
// h & 7 -> all 8 qt-blocks of one (b,h) land on the SAME XCD; its 16 owned
// K/V slices (~4 MB) fit one L2. Cuts K/V HBM refetch ~8x (T1 mechanism).
__device__ __forceinline__ ushort* swz(ushort* base, int row, int colb) {
  return (ushort*)((char*)base + row * 128 + (colb ^ ((row & 7) << 4)));
}

__global__ __launch_bounds__(256) void attn_fwd(
    const ushort* __restrict__ Q, const ushort* __restrict__ Km,
    const ushort* __restrict__ Vt, const float* __restrict__ Vsuf,
    const int* __restrict__ dlen, const int* __restrict__ elen,
    ushort* __restrict__ Oatt) {
  const int tid = threadIdx.x;
  const int lane = tid & 63, w = tid >> 6;
  const int g = lane >> 4, r = lane & 15;
  const int qt = blockIdx.y;               // 0..7
  const int b = blockIdx.x >> 4;           // 0..7
  const int h = blockIdx.x & 15;           // 0..15
  const int dl = dlen[b], el = elen[b];
  const float* VS = Vsuf + (size_t)(b * 16 + h) * 33 * 64;

  if (qt * 64 >= dl) {
    const int qrow = qt * 64 + w * 16 + g * 4;
#pragma unroll
    for (int dt = 0; dt < 4; ++dt) {
      const ushort hv = f2bf(VS[dt * 16 + r] * (1.0f / 2048.0f));
#pragma unroll
      for (int j = 0; j < 4; ++j)
        Oatt[(size_t)(b * 512 + qrow + j) * 1024 + h * 64 + dt * 16 + r] = hv;
    }
    return;
  }

  __shared__ ushort Ks[64 * 64];
  __shared__ ushort Vs[64 * 64];
  __shared__ ushort Ps[4 * 16 * 64];
  ushort* PsW = Ps + w * 16 * 64;
  const int qbase = qt * 64 + w * 16;

  s16x8 qf[2];
  {
    const ushort* qp = Q + (size_t)(b * 512 + qbase + r) * 1024 + h * 64 + g * 8;
    qf[0] = *(const s16x8*)qp;
    qf[1] = *(const s16x8*)(qp + 32);
  }

  f32x4 o[4] = {};
  float lrow[4] = {0.0f, 0.0f, 0.0f, 0.0f};
  bool qok[4];
#pragma unroll
  for (int j = 0; j < 4; ++j) qok[j] = (qbase + g * 4 + j) < dl;

  const int sr = tid >> 3;
  const int sc8 = (tid & 7) * 8;
  const int scb = sc8 * 2;
  const ushort* Kg = Km + (size_t)(b * 2048 + sr) * 1024 + h * 64 + sc8;
  const ushort* Vg = Vt + ((size_t)b * 1024 + h * 64 + sr) * 2048 + sc8;

  const int t_last = (el - 1) >> 6;

  s16x8 pk0, pk1, pv0, pv1;
  {
    pk0 = *(const s16x8*)(Kg);
    pk1 = *(const s16x8*)(Kg + (size_t)32 * 1024);
    pv0 = *(const s16x8*)(Vg);
    pv1 = *(const s16x8*)(Vg + (size_t)32 * 2048);
  }

  for (int t = 0; t <= t_last; ++t) {
    *(s16x8*)swz(Ks, sr, scb) = pk0;
    *(s16x8*)swz(Ks, sr + 32, scb) = pk1;
    *(s16x8*)swz(Vs, sr, scb) = pv0;
    *(s16x8*)swz(Vs, sr + 32, scb) = pv1;
    __syncthreads();

    if (t < t_last) {
      const int kv0 = (t + 1) * 64;
      pk0 = *(const s16x8*)(Kg + (size_t)kv0 * 1024);
      pk1 = *(const s16x8*)(Kg + (size_t)(kv0 + 32) * 1024);
      pv0 = *(const s16x8*)(Vg + kv0);
      pv1 = *(const s16x8*)(Vg + (size_t)32 * 2048 + kv0);
    }

    const int kv0 = t * 64;
    float p[4][4];
#pragma unroll
    for (int nt = 0; nt < 4; ++nt) {
      f32x4 s = {};
      s16x8 kf0 = *(const s16x8*)swz(Ks, nt * 16 + r, g * 16);
      s16x8 kf1 = *(const s16x8*)swz(Ks, nt * 16 + r, 64 + g * 16);
      __builtin_amdgcn_s_setprio(1);
      s = __builtin_amdgcn_mfma_f32_16x16x32_bf16(qf[0], kf0, s, 0, 0, 0);
      s = __builtin_amdgcn_mfma_f32_16x16x32_bf16(qf[1], kf1, s, 0, 0, 0);
      __builtin_amdgcn_s_setprio(0);
      const bool kok = (kv0 + nt * 16 + r) < el;
#pragma unroll
      for (int j = 0; j < 4; ++j) {
        const float pe = __builtin_amdgcn_exp2f(s[j]);
        p[nt][j] = (kok && qok[j]) ? pe : 1.0f;
      }
    }
#pragma unroll
    for (int nt = 0; nt < 4; ++nt)
#pragma unroll
      for (int j = 0; j < 4; ++j) lrow[j] += p[nt][j];

#pragma unroll
    for (int nt = 0; nt < 4; ++nt) {
#pragma unroll
      for (int jp = 0; jp < 4; jp += 2) {
        unsigned pk;
        asm("v_cvt_pk_bf16_f32 %0, %1, %2" : "=v"(pk) : "v"(p[nt][jp]), "v"(p[nt][jp + 1]));
        *swz(PsW, g * 4 + jp, (nt * 16 + r) * 2) = (ushort)pk;
        *swz(PsW, g * 4 + jp + 1, (nt * 16 + r) * 2) = (ushort)(pk >> 16);
      }
    }

#pragma unroll
    for (int kc = 0; kc < 2; ++kc) {
      s16x8 pf = *(const s16x8*)swz(PsW, r, kc * 64 + g * 16);
      __builtin_amdgcn_s_setprio(1);
#pragma unroll
      for (int dt = 0; dt < 4; ++dt) {
        s16x8 vf = *(const s16x8*)swz(Vs, dt * 16 + r, kc * 64 + g * 16);
        o[dt] = __builtin_amdgcn_mfma_f32_16x16x32_bf16(pf, vf, o[dt], 0, 0, 0);
      }
      __builtin_amdgcn_s_setprio(0);
    }
    __syncthreads();
  }

  const float tailcnt = (float)(2048 - (t_last + 1) * 64);
  const float* VT = VS + (t_last + 1) * 64;
#pragma unroll
  for (int dt = 0; dt < 4; ++dt) {
    const float tv = VT[dt * 16 + r];
#pragma unroll
    for (int j = 0; j < 4; ++j) o[dt][j] += tv;
  }

  float inv[4];
#pragma unroll
  for (int j = 0; j < 4; ++j) {
    float s = lrow[j];
    s += __shfl_xor(s, 1);
    s += __shfl_xor(s, 2);
    s += __shfl_xor(s, 4);
    s += __shfl_xor(s, 8);
    inv[j] = 1.0f / (s + tailcnt);
  }
#pragma unroll
  for (int dt = 0; dt < 4; ++dt)
#pragma unroll
    for (int j = 0; j < 4; ++j)
      Oatt[(size_t)(b * 512 + qbase + g * 4 + j) * 1024 + h * 64 + dt * 16 + r] =
          f2bf(o[dt][j] * inv[j]);
}

// ---------------- launch ----------------
extern "C" void kernel_launch(void* const* d_in, const int* in_sizes, int n_in,
                              void* d_out, int out_size, void* d_ws, size_t ws_size,
                              hipStream_t stream) {
  const float* enc  = (const float*)d_in[0];
  const float* fq   = (const float*)d_in[1];
  const int* dlen   = (const int*)d_in[2];
  const int* elen   = (const int*)d_in[3];
  const float* wq_w = (const float*)d_in[4];
  const float* wq_b = (const float*)d_in[5];
  const float* wk_w = (const float*)d_in[6];
  const float* wk_b = (const float*)d_in[7];
  const float* wv_w = (const float*)d_in[8];
  const float* wv_b = (const float*)d_in[9];
  const float* wo_w = (const float*)d_in[10];
  const float* wo_b = (const float*)d_in[11];

  char* ws = (char*)d_ws;  // all within 128MB; attw aliases fq16 (dead by attn time)
  ushort* enc16 = (ushort*)(ws + 0);           // 32 MB
  ushort* fq16  = (ushort*)(ws + 33554432);    // 8 MB
  ushort* attw  = (ushort*)(ws + 33554432);    // alias of fq16
  ushort* wq16  = (ushort*)(ws + 41943040);    // 2 MB
  ushort* wk16  = (ushort*)(ws + 44040192);    // 2 MB  | adjacent: [wk;wv] = B concat
  ushort* wv16  = (ushort*)(ws + 46137344);    // 2 MB  |
  ushort* wo16  = (ushort*)(ws + 48234496);    // 2 MB
  float*  Vsuf  = (float*)(ws + 50331648);     // ~1.06 MB (Tsum/Vsuf)
  ushort* Qw    = (ushort*)(ws + 52428800);    // 8 MB
  ushort* Kw    = (ushort*)(ws + 60817408);    // 32 MB
  ushort* Vtw   = (ushort*)(ws + 94371840);    // 32 MB, ends 126877696 < 128MB

  cvt_all<<<4096, 256, 0, stream>>>((const float4*)enc, (const float4*)fq,
                                    (const float4*)wq_w, (const float4*)wk_w,
                                    (const float4*)wv_w, (const float4*)wo_w,
                                    enc16, fq16, wq16, wk16, wv16, wo16);

  const float qscale = 0.125f * 1.44269504088896340736f;
  gemm256_fused<<<576, 512, 0, stream>>>(enc16, fq16, wk16, wq16, wk_b, wv_b, wq_b,
                                         Kw, Vtw, Qw, Vsuf, dlen, elen, qscale);
  vsuffix<<<128, 64, 0, stream>>>(Vsuf);

  attn_fwd<<<dim3(128, 8), 256, 0, stream>>>(Qw, Kw, Vtw, Vsuf, dlen, elen, attw);

  oproj<<<dim3(32, 8), 256, 0, stream>>>(attw, wo16, wo_b, (float*)d_out, 4096, 1024, 1024);
}